// Round 4
// baseline (489.056 us; speedup 1.0000x reference)
//
#include <hip/hip_runtime.h>

#define N_NODES 100000
#define N_EDGES 1600000
#define HDIM 64
#define SCAN_BS 256
#define NBLK ((N_NODES + SCAN_BS - 1) / SCAN_BS)   // 391
#define KPRIV 8

// ---------------- privatized degree computation ----------------
// partition k = blockIdx & 7; deg_in partition must match fill_csr's.
__global__ void degree_priv_kernel(const int* __restrict__ src, const int* __restrict__ dst,
                                   int* __restrict__ deg_out_priv, int* __restrict__ deg_in_priv,
                                   int E) {
    int e = blockIdx.x * blockDim.x + threadIdx.x;
    int k = blockIdx.x & (KPRIV - 1);
    if (e < E) {
        atomicAdd(&deg_out_priv[(size_t)k * N_NODES + src[e]], 1);
        atomicAdd(&deg_in_priv[(size_t)k * N_NODES + dst[e]], 1);
    }
}

// totals + inv-sqrt norms + per-partition exclusive prefix (pre-offset) into cursor_priv
__global__ void reduce_priv_kernel(const int* __restrict__ deg_out_priv,
                                   const int* __restrict__ deg_in_priv,
                                   float* __restrict__ inv_out, float* __restrict__ inv_in,
                                   int* __restrict__ deg_in, int* __restrict__ cursor_priv,
                                   int n) {
    int i = blockIdx.x * blockDim.x + threadIdx.x;
    if (i >= n) return;
    int so = 0;
#pragma unroll
    for (int k = 0; k < KPRIV; ++k) so += deg_out_priv[(size_t)k * N_NODES + i];
    int run = 0;
#pragma unroll
    for (int k = 0; k < KPRIV; ++k) {
        cursor_priv[(size_t)k * N_NODES + i] = run;   // sub-offset; offsets[i] added later
        run += deg_in_priv[(size_t)k * N_NODES + i];
    }
    deg_in[i] = run;
    inv_out[i] = rsqrtf((float)max(so, 1));
    inv_in[i]  = rsqrtf((float)max(run, 1));
}

// ---------------- scan (exclusive prefix sum of deg_in -> CSR offsets) ----------------
__global__ void blocksum_kernel(const int* __restrict__ deg_in, int* __restrict__ bs) {
    int t = threadIdx.x, b = blockIdx.x;
    int i = b * SCAN_BS + t;
    int v = (i < N_NODES) ? deg_in[i] : 0;
    for (int off = 32; off > 0; off >>= 1) v += __shfl_down(v, off, 64);
    __shared__ int w[4];
    if ((t & 63) == 0) w[t >> 6] = v;
    __syncthreads();
    if (t == 0) bs[b] = w[0] + w[1] + w[2] + w[3];
}

__global__ void scan_blocksums(const int* __restrict__ bs, int* __restrict__ boff,
                               int* __restrict__ offsets) {
    __shared__ int s[512];
    int t = threadIdx.x;
    int v = (t < NBLK) ? bs[t] : 0;
    s[t] = v;
    __syncthreads();
    for (int off = 1; off < 512; off <<= 1) {
        int x = (t >= off) ? s[t - off] : 0;
        __syncthreads();
        s[t] += x;
        __syncthreads();
    }
    if (t < NBLK) boff[t] = s[t] - v;
    if (t == 0) offsets[N_NODES] = N_EDGES;
}

__global__ void scan_final(const int* __restrict__ deg_in, const int* __restrict__ boff,
                           int* __restrict__ offsets) {
    __shared__ int s[SCAN_BS];
    int t = threadIdx.x, b = blockIdx.x;
    int i = b * SCAN_BS + t;
    int v = (i < N_NODES) ? deg_in[i] : 0;
    s[t] = v;
    __syncthreads();
    for (int off = 1; off < SCAN_BS; off <<= 1) {
        int x = (t >= off) ? s[t - off] : 0;
        __syncthreads();
        s[t] += x;
        __syncthreads();
    }
    if (i < N_NODES) offsets[i] = s[t] - v + boff[b];
}

// cursor_priv[k][i] += offsets[i]
__global__ void init_cursor_kernel(const int* __restrict__ offsets, int* __restrict__ cursor_priv,
                                   int n) {
    int i = blockIdx.x * blockDim.x + threadIdx.x;
    if (i >= n) return;
    int o = offsets[i];
#pragma unroll
    for (int k = 0; k < KPRIV; ++k) cursor_priv[(size_t)k * N_NODES + i] += o;
}

// ---------------- CSR fill (privatized cursor): csr_src[slot of dst] = src ----------------
__global__ void fill_csr(const int* __restrict__ src, const int* __restrict__ dst,
                         int* __restrict__ cursor_priv, int* __restrict__ csr_src, int E) {
    int e = blockIdx.x * blockDim.x + threadIdx.x;
    int k = blockIdx.x & (KPRIV - 1);
    if (e < E) {
        int pos = atomicAdd(&cursor_priv[(size_t)k * N_NODES + dst[e]], 1);
        csr_src[pos] = src[e];
    }
}

// ---------------- dense: hw = (h * inv_out[:,None]) @ W ----------------
__global__ void dense_kernel(const float* __restrict__ h, const float* __restrict__ inv_out,
                             const float* __restrict__ W, float* __restrict__ hw, int n) {
    __shared__ float Wlds[HDIM * HDIM];     // 16 KB
    __shared__ float Alds[HDIM][HDIM + 1];  // padded
    int t = threadIdx.x;
    int r0 = blockIdx.x * 64;

    for (int i = t; i < HDIM * HDIM / 4; i += 256)
        ((float4*)Wlds)[i] = ((const float4*)W)[i];

    for (int i = t; i < 1024; i += 256) {   // 64 rows x 16 float4
        int r = i >> 4;
        int c4 = i & 15;
        int row = r0 + r;
        float4 v = make_float4(0.f, 0.f, 0.f, 0.f);
        float s = 0.f;
        if (row < n) {
            v = ((const float4*)h)[(long long)row * 16 + c4];
            s = inv_out[row];
        }
        Alds[r][c4 * 4 + 0] = v.x * s;
        Alds[r][c4 * 4 + 1] = v.y * s;
        Alds[r][c4 * 4 + 2] = v.z * s;
        Alds[r][c4 * 4 + 3] = v.w * s;
    }
    __syncthreads();

    int tx = t & 15;
    int ty = t >> 4;
    float4 acc0 = make_float4(0.f, 0.f, 0.f, 0.f);
    float4 acc1 = acc0, acc2 = acc0, acc3 = acc0;

#pragma unroll 8
    for (int k = 0; k < HDIM; ++k) {
        float4 w = ((const float4*)(Wlds + k * HDIM))[tx];
        float a0 = Alds[4 * ty + 0][k];
        float a1 = Alds[4 * ty + 1][k];
        float a2 = Alds[4 * ty + 2][k];
        float a3 = Alds[4 * ty + 3][k];
        acc0.x = fmaf(a0, w.x, acc0.x); acc0.y = fmaf(a0, w.y, acc0.y);
        acc0.z = fmaf(a0, w.z, acc0.z); acc0.w = fmaf(a0, w.w, acc0.w);
        acc1.x = fmaf(a1, w.x, acc1.x); acc1.y = fmaf(a1, w.y, acc1.y);
        acc1.z = fmaf(a1, w.z, acc1.z); acc1.w = fmaf(a1, w.w, acc1.w);
        acc2.x = fmaf(a2, w.x, acc2.x); acc2.y = fmaf(a2, w.y, acc2.y);
        acc2.z = fmaf(a2, w.z, acc2.z); acc2.w = fmaf(a2, w.w, acc2.w);
        acc3.x = fmaf(a3, w.x, acc3.x); acc3.y = fmaf(a3, w.y, acc3.y);
        acc3.z = fmaf(a3, w.z, acc3.z); acc3.w = fmaf(a3, w.w, acc3.w);
    }

    int rb = r0 + 4 * ty;
    if (rb + 0 < n) ((float4*)hw)[(long long)(rb + 0) * 16 + tx] = acc0;
    if (rb + 1 < n) ((float4*)hw)[(long long)(rb + 1) * 16 + tx] = acc1;
    if (rb + 2 < n) ((float4*)hw)[(long long)(rb + 2) * 16 + tx] = acc2;
    if (rb + 3 < n) ((float4*)hw)[(long long)(rb + 3) * 16 + tx] = acc3;
}

// ---------------- gather: out = relu(inv_in * sum_{in-edges} hw[src] + b) ----------------
__global__ void gather_kernel(const float* __restrict__ hw, const float* __restrict__ inv_in,
                              const int* __restrict__ offsets, const int* __restrict__ csr_src,
                              const float* __restrict__ bias, float* __restrict__ out, int n) {
    int t = threadIdx.x;
    int wave = t >> 6, lane = t & 63;
    int row = blockIdx.x * 4 + wave;
    if (row >= n) return;
    int group = lane >> 4, gl = lane & 15;

    int start = offsets[row];
    int end   = offsets[row + 1];

    float4 acc = make_float4(0.f, 0.f, 0.f, 0.f);
#pragma unroll 2
    for (int j = start + group; j < end; j += 4) {
        int s = csr_src[j];
        float4 v = ((const float4*)hw)[(long long)s * 16 + gl];
        acc.x += v.x; acc.y += v.y; acc.z += v.z; acc.w += v.w;
    }
    acc.x += __shfl_down(acc.x, 32, 64);
    acc.y += __shfl_down(acc.y, 32, 64);
    acc.z += __shfl_down(acc.z, 32, 64);
    acc.w += __shfl_down(acc.w, 32, 64);
    acc.x += __shfl_down(acc.x, 16, 64);
    acc.y += __shfl_down(acc.y, 16, 64);
    acc.z += __shfl_down(acc.z, 16, 64);
    acc.w += __shfl_down(acc.w, 16, 64);

    if (group == 0) {
        float sc = inv_in[row];
        float4 b4 = ((const float4*)bias)[gl];
        float4 r;
        r.x = fmaxf(fmaf(acc.x, sc, b4.x), 0.f);
        r.y = fmaxf(fmaf(acc.y, sc, b4.y), 0.f);
        r.z = fmaxf(fmaf(acc.z, sc, b4.z), 0.f);
        r.w = fmaxf(fmaf(acc.w, sc, b4.w), 0.f);
        ((float4*)out)[(long long)row * 16 + gl] = r;
    }
}

extern "C" void kernel_launch(void* const* d_in, const int* in_sizes, int n_in,
                              void* d_out, int out_size, void* d_ws, size_t ws_size,
                              hipStream_t stream) {
    const float* features = (const float*)d_in[0];   // [N, 64]
    const float* W        = (const float*)d_in[1];   // [64, 64]
    const float* b        = (const float*)d_in[2];   // [64]
    const int*   src      = (const int*)d_in[3];     // [E]
    const int*   dst      = (const int*)d_in[4];     // [E]

    float* out = (float*)d_out;                      // [N, 64] — also inter-layer temp

    // workspace layout (4-byte words); ~33.6 MB total
    float* ws = (float*)d_ws;
    float* hw = ws;                                  // N*H words (25.6 MB)
    // --- overlay inside hw (only live before dense_kernel) ---
    int* deg_out_priv = (int*)hw;                    // 8*N
    int* deg_in_priv  = deg_out_priv + (size_t)KPRIV * N_NODES;  // 8*N
    int* cursor_priv  = deg_in_priv + (size_t)KPRIV * N_NODES;   // 8*N  (2.4M words < 6.4M)
    // --- persistent ---
    float* inv_out = ws + (size_t)N_NODES * HDIM;    // N
    float* inv_in  = inv_out + N_NODES;              // N
    int*   deg_in  = (int*)(inv_in + N_NODES);       // N
    int*   offsets = deg_in + N_NODES;               // N+1
    int*   bs      = offsets + N_NODES + 1;          // NBLK
    int*   boff    = bs + NBLK;                      // NBLK
    int*   csr_src = boff + NBLK;                    // E

    const int E = N_EDGES;
    const int N = N_NODES;

    // privatized degrees
    hipMemsetAsync(deg_out_priv, 0, 2 * (size_t)KPRIV * N_NODES * sizeof(int), stream);
    degree_priv_kernel<<<(E + 255) / 256, 256, 0, stream>>>(src, dst, deg_out_priv, deg_in_priv, E);
    reduce_priv_kernel<<<(N + 255) / 256, 256, 0, stream>>>(deg_out_priv, deg_in_priv,
                                                            inv_out, inv_in, deg_in, cursor_priv, N);

    // CSR offsets (by dst)
    blocksum_kernel<<<NBLK, SCAN_BS, 0, stream>>>(deg_in, bs);
    scan_blocksums<<<1, 512, 0, stream>>>(bs, boff, offsets);
    scan_final<<<NBLK, SCAN_BS, 0, stream>>>(deg_in, boff, offsets);
    init_cursor_kernel<<<(N + 255) / 256, 256, 0, stream>>>(offsets, cursor_priv, N);
    fill_csr<<<(E + 255) / 256, 256, 0, stream>>>(src, dst, cursor_priv, csr_src, E);

    int dense_blocks  = (N + 63) / 64;
    int gather_blocks = (N + 3) / 4;

    // layer 1: features -> hw -> out
    dense_kernel<<<dense_blocks, 256, 0, stream>>>(features, inv_out, W, hw, N);
    gather_kernel<<<gather_blocks, 256, 0, stream>>>(hw, inv_in, offsets, csr_src, b, out, N);

    // layer 2: out -> hw -> out
    dense_kernel<<<dense_blocks, 256, 0, stream>>>(out, inv_out, W, hw, N);
    gather_kernel<<<gather_blocks, 256, 0, stream>>>(hw, inv_in, offsets, csr_src, b, out, N);
}

// Round 5
// 317.748 us; speedup vs baseline: 1.5391x; 1.5391x over previous
//
#include <hip/hip_runtime.h>

#define N_NODES 100000
#define N_EDGES 1600000
#define HDIM 64
#define NPB 512                                  // nodes per bucket (pow2)
#define NPB_SHIFT 9
#define NBUCK ((N_NODES + NPB - 1) / NPB)        // 196
#define NCHUNK 256                               // phase-A blocks
#define CHUNK (N_EDGES / NCHUNK)                 // 6250 edges/block

// ---------------- K1: global bucket histograms (dst-buckets and src-buckets) ----------------
__global__ void hist_kernel(const int* __restrict__ src, const int* __restrict__ dst,
                            int* __restrict__ histD, int* __restrict__ histS) {
    __shared__ int hD[NBUCK], hS[NBUCK];
    int t = threadIdx.x;
    for (int i = t; i < NBUCK; i += 256) { hD[i] = 0; hS[i] = 0; }
    __syncthreads();
    int e0 = blockIdx.x * CHUNK;
    for (int i = t; i < CHUNK; i += 256) {
        atomicAdd(&hD[dst[e0 + i] >> NPB_SHIFT], 1);
        atomicAdd(&hS[src[e0 + i] >> NPB_SHIFT], 1);
    }
    __syncthreads();
    for (int i = t; i < NBUCK; i += 256) {
        if (hD[i]) atomicAdd(&histD[i], hD[i]);
        if (hS[i]) atomicAdd(&histS[i], hS[i]);
    }
}

// ---------------- K2: exclusive scan of bucket counts -> bases + cursors ----------------
__global__ void scan_buckets(const int* __restrict__ histD, const int* __restrict__ histS,
                             int* __restrict__ baseD, int* __restrict__ cursorD,
                             int* __restrict__ baseS, int* __restrict__ cursorS) {
    __shared__ int sD[NBUCK], sS[NBUCK];
    int t = threadIdx.x;
    if (t < NBUCK) { sD[t] = histD[t]; sS[t] = histS[t]; }
    __syncthreads();
    if (t == 0) {
        int rd = 0, rs = 0;
        for (int b = 0; b < NBUCK; ++b) {
            int d = sD[b], s2 = sS[b];
            sD[b] = rd; sS[b] = rs;
            rd += d; rs += s2;
        }
    }
    __syncthreads();
    if (t < NBUCK) {
        baseD[t] = sD[t]; cursorD[t] = sD[t];
        baseS[t] = sS[t]; cursorS[t] = sS[t];
    }
}

// ---------------- K3: place edges into bucket-partitioned staging buffers ----------------
// bufD entry: src | (local_dst << 17)   (src < 2^17, local_dst < 512)
// bufS entry: local_src (u16)
__global__ void place_kernel(const int* __restrict__ src, const int* __restrict__ dst,
                             int* __restrict__ cursorD, int* __restrict__ cursorS,
                             unsigned int* __restrict__ bufD, unsigned short* __restrict__ bufS) {
    __shared__ int hD[NBUCK], hS[NBUCK];
    __shared__ int curD[NBUCK], curS[NBUCK];
    int t = threadIdx.x;
    for (int i = t; i < NBUCK; i += 256) { hD[i] = 0; hS[i] = 0; }
    __syncthreads();
    int e0 = blockIdx.x * CHUNK;
    for (int i = t; i < CHUNK; i += 256) {
        atomicAdd(&hD[dst[e0 + i] >> NPB_SHIFT], 1);
        atomicAdd(&hS[src[e0 + i] >> NPB_SHIFT], 1);
    }
    __syncthreads();
    for (int i = t; i < NBUCK; i += 256) {
        curD[i] = hD[i] ? atomicAdd(&cursorD[i], hD[i]) : 0;
        curS[i] = hS[i] ? atomicAdd(&cursorS[i], hS[i]) : 0;
    }
    __syncthreads();
    for (int i = t; i < CHUNK; i += 256) {
        int s = src[e0 + i], d = dst[e0 + i];
        int bd = d >> NPB_SHIFT, bs = s >> NPB_SHIFT;
        int pd = atomicAdd(&curD[bd], 1);
        bufD[pd] = (unsigned)s | ((unsigned)(d & (NPB - 1)) << 17);
        int ps = atomicAdd(&curS[bs], 1);
        bufS[ps] = (unsigned short)(s & (NPB - 1));
    }
}

// ---------------- K4: per dst-bucket: counts -> offsets/inv_in, place csr_src ----------------
__global__ void bucket_dst_kernel(const unsigned int* __restrict__ bufD,
                                  const int* __restrict__ baseD, const int* __restrict__ histD,
                                  int* __restrict__ csr_src, int* __restrict__ offsets,
                                  float* __restrict__ inv_in) {
    __shared__ int cnt[NPB], pre[NPB], cur[NPB];
    int b = blockIdx.x, t = threadIdx.x;   // blockDim = 512
    int ebase = baseD[b], ecnt = histD[b];
    cnt[t] = 0;
    __syncthreads();
    for (int i = t; i < ecnt; i += NPB)
        atomicAdd(&cnt[bufD[ebase + i] >> 17], 1);
    __syncthreads();
    int v = cnt[t];
    pre[t] = v;
    __syncthreads();
    for (int off = 1; off < NPB; off <<= 1) {
        int x = (t >= off) ? pre[t - off] : 0;
        __syncthreads();
        pre[t] += x;
        __syncthreads();
    }
    int excl = pre[t] - v;     // exclusive prefix within bucket
    cur[t] = excl;
    int node = b * NPB + t;
    if (node < N_NODES) {
        offsets[node] = ebase + excl;
        inv_in[node] = rsqrtf((float)max(v, 1));
    } else if (node == N_NODES) {
        offsets[N_NODES] = N_EDGES;
    }
    __syncthreads();
    for (int i = t; i < ecnt; i += NPB) {
        unsigned int en = bufD[ebase + i];
        int l = (int)(en >> 17);
        int pos = atomicAdd(&cur[l], 1);
        csr_src[ebase + pos] = (int)(en & 0x1FFFFu);
    }
}

// ---------------- K5: per src-bucket: counts -> inv_out ----------------
__global__ void bucket_src_kernel(const unsigned short* __restrict__ bufS,
                                  const int* __restrict__ baseS, const int* __restrict__ histS,
                                  float* __restrict__ inv_out) {
    __shared__ int cnt[NPB];
    int b = blockIdx.x, t = threadIdx.x;   // blockDim = 512
    int ebase = baseS[b], ecnt = histS[b];
    cnt[t] = 0;
    __syncthreads();
    for (int i = t; i < ecnt; i += NPB)
        atomicAdd(&cnt[(int)bufS[ebase + i]], 1);
    __syncthreads();
    int node = b * NPB + t;
    if (node < N_NODES) inv_out[node] = rsqrtf((float)max(cnt[t], 1));
}

// ---------------- dense: hw = (h * inv_out[:,None]) @ W ----------------
__global__ void dense_kernel(const float* __restrict__ h, const float* __restrict__ inv_out,
                             const float* __restrict__ W, float* __restrict__ hw, int n) {
    __shared__ float Wlds[HDIM * HDIM];
    __shared__ float Alds[HDIM][HDIM + 1];
    int t = threadIdx.x;
    int r0 = blockIdx.x * 64;

    for (int i = t; i < HDIM * HDIM / 4; i += 256)
        ((float4*)Wlds)[i] = ((const float4*)W)[i];

    for (int i = t; i < 1024; i += 256) {
        int r = i >> 4;
        int c4 = i & 15;
        int row = r0 + r;
        float4 v = make_float4(0.f, 0.f, 0.f, 0.f);
        float s = 0.f;
        if (row < n) {
            v = ((const float4*)h)[(long long)row * 16 + c4];
            s = inv_out[row];
        }
        Alds[r][c4 * 4 + 0] = v.x * s;
        Alds[r][c4 * 4 + 1] = v.y * s;
        Alds[r][c4 * 4 + 2] = v.z * s;
        Alds[r][c4 * 4 + 3] = v.w * s;
    }
    __syncthreads();

    int tx = t & 15;
    int ty = t >> 4;
    float4 acc0 = make_float4(0.f, 0.f, 0.f, 0.f);
    float4 acc1 = acc0, acc2 = acc0, acc3 = acc0;

#pragma unroll 8
    for (int k = 0; k < HDIM; ++k) {
        float4 w = ((const float4*)(Wlds + k * HDIM))[tx];
        float a0 = Alds[4 * ty + 0][k];
        float a1 = Alds[4 * ty + 1][k];
        float a2 = Alds[4 * ty + 2][k];
        float a3 = Alds[4 * ty + 3][k];
        acc0.x = fmaf(a0, w.x, acc0.x); acc0.y = fmaf(a0, w.y, acc0.y);
        acc0.z = fmaf(a0, w.z, acc0.z); acc0.w = fmaf(a0, w.w, acc0.w);
        acc1.x = fmaf(a1, w.x, acc1.x); acc1.y = fmaf(a1, w.y, acc1.y);
        acc1.z = fmaf(a1, w.z, acc1.z); acc1.w = fmaf(a1, w.w, acc1.w);
        acc2.x = fmaf(a2, w.x, acc2.x); acc2.y = fmaf(a2, w.y, acc2.y);
        acc2.z = fmaf(a2, w.z, acc2.z); acc2.w = fmaf(a2, w.w, acc2.w);
        acc3.x = fmaf(a3, w.x, acc3.x); acc3.y = fmaf(a3, w.y, acc3.y);
        acc3.z = fmaf(a3, w.z, acc3.z); acc3.w = fmaf(a3, w.w, acc3.w);
    }

    int rb = r0 + 4 * ty;
    if (rb + 0 < n) ((float4*)hw)[(long long)(rb + 0) * 16 + tx] = acc0;
    if (rb + 1 < n) ((float4*)hw)[(long long)(rb + 1) * 16 + tx] = acc1;
    if (rb + 2 < n) ((float4*)hw)[(long long)(rb + 2) * 16 + tx] = acc2;
    if (rb + 3 < n) ((float4*)hw)[(long long)(rb + 3) * 16 + tx] = acc3;
}

// ---------------- gather: out = relu(inv_in * sum_{in-edges} hw[src] + b) ----------------
__global__ void gather_kernel(const float* __restrict__ hw, const float* __restrict__ inv_in,
                              const int* __restrict__ offsets, const int* __restrict__ csr_src,
                              const float* __restrict__ bias, float* __restrict__ out, int n) {
    int t = threadIdx.x;
    int wave = t >> 6, lane = t & 63;
    int row = blockIdx.x * 4 + wave;
    if (row >= n) return;
    int group = lane >> 4, gl = lane & 15;

    int start = offsets[row];
    int end   = offsets[row + 1];

    float4 acc = make_float4(0.f, 0.f, 0.f, 0.f);
#pragma unroll 2
    for (int j = start + group; j < end; j += 4) {
        int s = csr_src[j];
        float4 v = ((const float4*)hw)[(long long)s * 16 + gl];
        acc.x += v.x; acc.y += v.y; acc.z += v.z; acc.w += v.w;
    }
    acc.x += __shfl_down(acc.x, 32, 64);
    acc.y += __shfl_down(acc.y, 32, 64);
    acc.z += __shfl_down(acc.z, 32, 64);
    acc.w += __shfl_down(acc.w, 32, 64);
    acc.x += __shfl_down(acc.x, 16, 64);
    acc.y += __shfl_down(acc.y, 16, 64);
    acc.z += __shfl_down(acc.z, 16, 64);
    acc.w += __shfl_down(acc.w, 16, 64);

    if (group == 0) {
        float sc = inv_in[row];
        float4 b4 = ((const float4*)bias)[gl];
        float4 r;
        r.x = fmaxf(fmaf(acc.x, sc, b4.x), 0.f);
        r.y = fmaxf(fmaf(acc.y, sc, b4.y), 0.f);
        r.z = fmaxf(fmaf(acc.z, sc, b4.z), 0.f);
        r.w = fmaxf(fmaf(acc.w, sc, b4.w), 0.f);
        ((float4*)out)[(long long)row * 16 + gl] = r;
    }
}

extern "C" void kernel_launch(void* const* d_in, const int* in_sizes, int n_in,
                              void* d_out, int out_size, void* d_ws, size_t ws_size,
                              hipStream_t stream) {
    const float* features = (const float*)d_in[0];   // [N, 64]
    const float* W        = (const float*)d_in[1];   // [64, 64]
    const float* b        = (const float*)d_in[2];   // [64]
    const int*   src      = (const int*)d_in[3];     // [E]
    const int*   dst      = (const int*)d_in[4];     // [E]

    float* out = (float*)d_out;                      // [N, 64] — also inter-layer temp

    // workspace layout (4-byte words); ~33.3 MB total
    float* ws = (float*)d_ws;
    float* hw = ws;                                  // N*H words (25.6 MB)
    // --- overlay inside hw (dead before dense_kernel runs) ---
    unsigned int*   bufD = (unsigned int*)hw;                    // E words (6.4 MB)
    unsigned short* bufS = (unsigned short*)(bufD + N_EDGES);    // E u16   (3.2 MB)
    // --- persistent ---
    float* inv_out = ws + (size_t)N_NODES * HDIM;    // N
    float* inv_in  = inv_out + N_NODES;              // N
    int*   offsets = (int*)(inv_in + N_NODES);       // N+1
    int*   csr_src = offsets + N_NODES + 1;          // E
    int*   histD   = csr_src + N_EDGES;              // NBUCK
    int*   histS   = histD + NBUCK;                  // NBUCK (contiguous with histD for memset)
    int*   baseD   = histS + NBUCK;                  // NBUCK
    int*   baseS   = baseD + NBUCK;                  // NBUCK
    int*   cursorD = baseS + NBUCK;                  // NBUCK
    int*   cursorS = cursorD + NBUCK;                // NBUCK

    const int N = N_NODES;

    // CSR + degrees via bucketed counting sort (no per-edge global atomics)
    hipMemsetAsync(histD, 0, 2 * NBUCK * sizeof(int), stream);
    hist_kernel<<<NCHUNK, 256, 0, stream>>>(src, dst, histD, histS);
    scan_buckets<<<1, 256, 0, stream>>>(histD, histS, baseD, cursorD, baseS, cursorS);
    place_kernel<<<NCHUNK, 256, 0, stream>>>(src, dst, cursorD, cursorS, bufD, bufS);
    bucket_dst_kernel<<<NBUCK, NPB, 0, stream>>>(bufD, baseD, histD, csr_src, offsets, inv_in);
    bucket_src_kernel<<<NBUCK, NPB, 0, stream>>>(bufS, baseS, histS, inv_out);

    int dense_blocks  = (N + 63) / 64;
    int gather_blocks = (N + 3) / 4;

    // layer 1: features -> hw -> out
    dense_kernel<<<dense_blocks, 256, 0, stream>>>(features, inv_out, W, hw, N);
    gather_kernel<<<gather_blocks, 256, 0, stream>>>(hw, inv_in, offsets, csr_src, b, out, N);

    // layer 2: out -> hw -> out
    dense_kernel<<<dense_blocks, 256, 0, stream>>>(out, inv_out, W, hw, N);
    gather_kernel<<<gather_blocks, 256, 0, stream>>>(hw, inv_in, offsets, csr_src, b, out, N);
}

// Round 6
// 301.138 us; speedup vs baseline: 1.6240x; 1.0552x over previous
//
#include <hip/hip_runtime.h>

#define N_NODES 100000
#define N_EDGES 1600000
#define HDIM 64
#define NPB 512                                  // nodes per bucket (pow2)
#define NPB_SHIFT 9
#define NBUCK ((N_NODES + NPB - 1) / NPB)        // 196
#define NCHUNK 256                               // phase-A blocks (== blockDim of scan)
#define CHUNK (N_EDGES / NCHUNK)                 // 6250 edges/block

// ---------------- K1: per-chunk bucket histograms -> global (no global atomics) ----------------
__global__ void hist_kernel(const int* __restrict__ src, const int* __restrict__ dst,
                            int* __restrict__ hbD, int* __restrict__ hbS) {
    __shared__ int hD[NBUCK], hS[NBUCK];
    int t = threadIdx.x, blk = blockIdx.x;
    for (int i = t; i < NBUCK; i += 256) { hD[i] = 0; hS[i] = 0; }
    __syncthreads();
    int e0 = blk * CHUNK;
    for (int i = t; i < CHUNK; i += 256) {
        atomicAdd(&hD[dst[e0 + i] >> NPB_SHIFT], 1);
        atomicAdd(&hS[src[e0 + i] >> NPB_SHIFT], 1);
    }
    __syncthreads();
    for (int i = t; i < NBUCK; i += 256) {
        hbD[i * NCHUNK + blk] = hD[i];
        hbS[i * NCHUNK + blk] = hS[i];
    }
}

// ---------------- K2a: per-bucket scan across chunks -> chunk prefixes + bucket totals ----------------
__global__ void chunk_scan_kernel(const int* __restrict__ hbD, const int* __restrict__ hbS,
                                  int* __restrict__ pbD, int* __restrict__ pbS,
                                  int* __restrict__ totD, int* __restrict__ totS) {
    __shared__ int s[NCHUNK];
    int b = blockIdx.x, t = threadIdx.x;   // blockDim = NCHUNK
    // dst
    int v = hbD[b * NCHUNK + t];
    s[t] = v;
    __syncthreads();
    for (int off = 1; off < NCHUNK; off <<= 1) {
        int x = (t >= off) ? s[t - off] : 0;
        __syncthreads(); s[t] += x; __syncthreads();
    }
    pbD[b * NCHUNK + t] = s[t] - v;
    if (t == NCHUNK - 1) totD[b] = s[t];
    __syncthreads();
    // src
    v = hbS[b * NCHUNK + t];
    s[t] = v;
    __syncthreads();
    for (int off = 1; off < NCHUNK; off <<= 1) {
        int x = (t >= off) ? s[t - off] : 0;
        __syncthreads(); s[t] += x; __syncthreads();
    }
    pbS[b * NCHUNK + t] = s[t] - v;
    if (t == NCHUNK - 1) totS[b] = s[t];
}

// ---------------- K2b: scan bucket totals -> bucket bases ----------------
__global__ void bucket_base_kernel(const int* __restrict__ totD, const int* __restrict__ totS,
                                   int* __restrict__ baseD, int* __restrict__ baseS) {
    __shared__ int s[256];
    int t = threadIdx.x;
    int v = (t < NBUCK) ? totD[t] : 0;
    s[t] = v;
    __syncthreads();
    for (int off = 1; off < 256; off <<= 1) {
        int x = (t >= off) ? s[t - off] : 0;
        __syncthreads(); s[t] += x; __syncthreads();
    }
    if (t < NBUCK) baseD[t] = s[t] - v;
    __syncthreads();
    v = (t < NBUCK) ? totS[t] : 0;
    s[t] = v;
    __syncthreads();
    for (int off = 1; off < 256; off <<= 1) {
        int x = (t >= off) ? s[t - off] : 0;
        __syncthreads(); s[t] += x; __syncthreads();
    }
    if (t < NBUCK) baseS[t] = s[t] - v;
}

// ---------------- K3: place edges into bucket-partitioned staging (LDS cursors only) ----------------
// bufD entry: src | (local_dst << 17)   (src < 2^17, local_dst < 512)
__global__ void place_kernel(const int* __restrict__ src, const int* __restrict__ dst,
                             const int* __restrict__ baseD, const int* __restrict__ pbD,
                             const int* __restrict__ baseS, const int* __restrict__ pbS,
                             unsigned int* __restrict__ bufD, unsigned short* __restrict__ bufS) {
    __shared__ int curD[NBUCK], curS[NBUCK];
    int t = threadIdx.x, blk = blockIdx.x;
    for (int i = t; i < NBUCK; i += 256) {
        curD[i] = baseD[i] + pbD[i * NCHUNK + blk];
        curS[i] = baseS[i] + pbS[i * NCHUNK + blk];
    }
    __syncthreads();
    int e0 = blk * CHUNK;
    for (int i = t; i < CHUNK; i += 256) {
        int s = src[e0 + i], d = dst[e0 + i];
        int pd = atomicAdd(&curD[d >> NPB_SHIFT], 1);
        bufD[pd] = (unsigned)s | ((unsigned)(d & (NPB - 1)) << 17);
        int ps = atomicAdd(&curS[s >> NPB_SHIFT], 1);
        bufS[ps] = (unsigned short)(s & (NPB - 1));
    }
}

// ---------------- K4: per dst-bucket: counts -> offsets/inv_in, place csr_src ----------------
__global__ void bucket_dst_kernel(const unsigned int* __restrict__ bufD,
                                  const int* __restrict__ baseD, const int* __restrict__ totD,
                                  int* __restrict__ csr_src, int* __restrict__ offsets,
                                  float* __restrict__ inv_in) {
    __shared__ int cnt[NPB], pre[NPB], cur[NPB];
    int b = blockIdx.x, t = threadIdx.x;   // blockDim = 512
    int ebase = baseD[b], ecnt = totD[b];
    cnt[t] = 0;
    __syncthreads();
    for (int i = t; i < ecnt; i += NPB)
        atomicAdd(&cnt[bufD[ebase + i] >> 17], 1);
    __syncthreads();
    int v = cnt[t];
    pre[t] = v;
    __syncthreads();
    for (int off = 1; off < NPB; off <<= 1) {
        int x = (t >= off) ? pre[t - off] : 0;
        __syncthreads(); pre[t] += x; __syncthreads();
    }
    int excl = pre[t] - v;
    cur[t] = excl;
    int node = b * NPB + t;
    if (node < N_NODES) {
        offsets[node] = ebase + excl;
        inv_in[node] = rsqrtf((float)max(v, 1));
    } else if (node == N_NODES) {
        offsets[N_NODES] = N_EDGES;
    }
    __syncthreads();
    for (int i = t; i < ecnt; i += NPB) {
        unsigned int en = bufD[ebase + i];
        int l = (int)(en >> 17);
        int pos = atomicAdd(&cur[l], 1);
        csr_src[ebase + pos] = (int)(en & 0x1FFFFu);
    }
}

// ---------------- K5: per src-bucket: counts -> inv_out ----------------
__global__ void bucket_src_kernel(const unsigned short* __restrict__ bufS,
                                  const int* __restrict__ baseS, const int* __restrict__ totS,
                                  float* __restrict__ inv_out) {
    __shared__ int cnt[NPB];
    int b = blockIdx.x, t = threadIdx.x;   // blockDim = 512
    int ebase = baseS[b], ecnt = totS[b];
    cnt[t] = 0;
    __syncthreads();
    for (int i = t; i < ecnt; i += NPB)
        atomicAdd(&cnt[(int)bufS[ebase + i]], 1);
    __syncthreads();
    int node = b * NPB + t;
    if (node < N_NODES) inv_out[node] = rsqrtf((float)max(cnt[t], 1));
}

// ---------------- dense: hw = (h * inv_out[:,None]) @ W  (32 rows/block) ----------------
__global__ void dense_kernel(const float* __restrict__ h, const float* __restrict__ inv_out,
                             const float* __restrict__ W, float* __restrict__ hw, int n) {
    __shared__ float Wlds[HDIM * HDIM];     // 16 KB
    __shared__ float Alds[32][HDIM + 1];    // 8.1 KB
    int t = threadIdx.x;
    int r0 = blockIdx.x * 32;

    for (int i = t; i < HDIM * HDIM / 4; i += 256)
        ((float4*)Wlds)[i] = ((const float4*)W)[i];

    for (int i = t; i < 512; i += 256) {    // 32 rows x 16 float4
        int r = i >> 4;
        int c4 = i & 15;
        int row = r0 + r;
        float4 v = make_float4(0.f, 0.f, 0.f, 0.f);
        float s = 0.f;
        if (row < n) {
            v = ((const float4*)h)[(long long)row * 16 + c4];
            s = inv_out[row];
        }
        Alds[r][c4 * 4 + 0] = v.x * s;
        Alds[r][c4 * 4 + 1] = v.y * s;
        Alds[r][c4 * 4 + 2] = v.z * s;
        Alds[r][c4 * 4 + 3] = v.w * s;
    }
    __syncthreads();

    int tx = t & 15;        // col quad
    int ty = t >> 4;        // 16 row-pairs: rows 2*ty, 2*ty+1
    float4 acc0 = make_float4(0.f, 0.f, 0.f, 0.f);
    float4 acc1 = acc0;

#pragma unroll 8
    for (int k = 0; k < HDIM; ++k) {
        float4 w = ((const float4*)(Wlds + k * HDIM))[tx];
        float a0 = Alds[2 * ty + 0][k];
        float a1 = Alds[2 * ty + 1][k];
        acc0.x = fmaf(a0, w.x, acc0.x); acc0.y = fmaf(a0, w.y, acc0.y);
        acc0.z = fmaf(a0, w.z, acc0.z); acc0.w = fmaf(a0, w.w, acc0.w);
        acc1.x = fmaf(a1, w.x, acc1.x); acc1.y = fmaf(a1, w.y, acc1.y);
        acc1.z = fmaf(a1, w.z, acc1.z); acc1.w = fmaf(a1, w.w, acc1.w);
    }

    int rb = r0 + 2 * ty;
    if (rb + 0 < n) ((float4*)hw)[(long long)(rb + 0) * 16 + tx] = acc0;
    if (rb + 1 < n) ((float4*)hw)[(long long)(rb + 1) * 16 + tx] = acc1;
}

// ---------------- gather: out = relu(inv_in * sum_{in-edges} hw[src] + b) ----------------
// one wave per dst row; coalesced index preload + shfl distribute -> independent row loads
__global__ void gather_kernel(const float* __restrict__ hw, const float* __restrict__ inv_in,
                              const int* __restrict__ offsets, const int* __restrict__ csr_src,
                              const float* __restrict__ bias, float* __restrict__ out, int n) {
    int t = threadIdx.x;
    int wave = t >> 6, lane = t & 63;
    int row = blockIdx.x * 4 + wave;
    if (row >= n) return;
    int group = lane >> 4, gl = lane & 15;

    int start = offsets[row];
    int end   = offsets[row + 1];

    float4 acc = make_float4(0.f, 0.f, 0.f, 0.f);
    for (int jb = start; jb < end; jb += 64) {
        int m = end - jb;
        if (m > 64) m = 64;
        int sidx = (lane < m) ? csr_src[jb + lane] : -1;
        int iters = (m + 3) >> 2;
#pragma unroll 4
        for (int it = 0; it < iters; ++it) {
            int jj = it * 4 + group;                 // < 64 always
            int s = __shfl(sidx, jj, 64);
            bool valid = (s >= 0);
            int s2 = valid ? s : 0;
            float4 v = ((const float4*)hw)[(long long)s2 * 16 + gl];
            if (valid) {
                acc.x += v.x; acc.y += v.y; acc.z += v.z; acc.w += v.w;
            }
        }
    }
    acc.x += __shfl_down(acc.x, 32, 64);
    acc.y += __shfl_down(acc.y, 32, 64);
    acc.z += __shfl_down(acc.z, 32, 64);
    acc.w += __shfl_down(acc.w, 32, 64);
    acc.x += __shfl_down(acc.x, 16, 64);
    acc.y += __shfl_down(acc.y, 16, 64);
    acc.z += __shfl_down(acc.z, 16, 64);
    acc.w += __shfl_down(acc.w, 16, 64);

    if (group == 0) {
        float sc = inv_in[row];
        float4 b4 = ((const float4*)bias)[gl];
        float4 r;
        r.x = fmaxf(fmaf(acc.x, sc, b4.x), 0.f);
        r.y = fmaxf(fmaf(acc.y, sc, b4.y), 0.f);
        r.z = fmaxf(fmaf(acc.z, sc, b4.z), 0.f);
        r.w = fmaxf(fmaf(acc.w, sc, b4.w), 0.f);
        ((float4*)out)[(long long)row * 16 + gl] = r;
    }
}

extern "C" void kernel_launch(void* const* d_in, const int* in_sizes, int n_in,
                              void* d_out, int out_size, void* d_ws, size_t ws_size,
                              hipStream_t stream) {
    const float* features = (const float*)d_in[0];   // [N, 64]
    const float* W        = (const float*)d_in[1];   // [64, 64]
    const float* b        = (const float*)d_in[2];   // [64]
    const int*   src      = (const int*)d_in[3];     // [E]
    const int*   dst      = (const int*)d_in[4];     // [E]

    float* out = (float*)d_out;                      // [N, 64] — also inter-layer temp

    // workspace layout (4-byte words); ~34.1 MB total
    float* ws = (float*)d_ws;
    float* hw = ws;                                  // N*H words (25.6 MB)
    // --- overlay inside hw (dead before dense_kernel runs) ---
    unsigned int*   bufD = (unsigned int*)hw;                    // E words (6.4 MB)
    unsigned short* bufS = (unsigned short*)(bufD + N_EDGES);    // E u16   (3.2 MB)
    // --- persistent ---
    float* inv_out = ws + (size_t)N_NODES * HDIM;    // N
    float* inv_in  = inv_out + N_NODES;              // N
    int*   offsets = (int*)(inv_in + N_NODES);       // N+1
    int*   csr_src = offsets + N_NODES + 1;          // E
    int*   hbD     = csr_src + N_EDGES;              // NBUCK*NCHUNK
    int*   hbS     = hbD + NBUCK * NCHUNK;           // NBUCK*NCHUNK
    int*   pbD     = hbS + NBUCK * NCHUNK;           // NBUCK*NCHUNK
    int*   pbS     = pbD + NBUCK * NCHUNK;           // NBUCK*NCHUNK
    int*   totD    = pbS + NBUCK * NCHUNK;           // NBUCK
    int*   totS    = totD + NBUCK;                   // NBUCK
    int*   baseD   = totS + NBUCK;                   // NBUCK
    int*   baseS   = baseD + NBUCK;                  // NBUCK

    const int N = N_NODES;

    // CSR + degrees via bucketed counting sort (zero global atomics)
    hist_kernel<<<NCHUNK, 256, 0, stream>>>(src, dst, hbD, hbS);
    chunk_scan_kernel<<<NBUCK, NCHUNK, 0, stream>>>(hbD, hbS, pbD, pbS, totD, totS);
    bucket_base_kernel<<<1, 256, 0, stream>>>(totD, totS, baseD, baseS);
    place_kernel<<<NCHUNK, 256, 0, stream>>>(src, dst, baseD, pbD, baseS, pbS, bufD, bufS);
    bucket_dst_kernel<<<NBUCK, NPB, 0, stream>>>(bufD, baseD, totD, csr_src, offsets, inv_in);
    bucket_src_kernel<<<NBUCK, NPB, 0, stream>>>(bufS, baseS, totS, inv_out);

    int dense_blocks  = (N + 31) / 32;
    int gather_blocks = (N + 3) / 4;

    // layer 1: features -> hw -> out
    dense_kernel<<<dense_blocks, 256, 0, stream>>>(features, inv_out, W, hw, N);
    gather_kernel<<<gather_blocks, 256, 0, stream>>>(hw, inv_in, offsets, csr_src, b, out, N);

    // layer 2: out -> hw -> out
    dense_kernel<<<dense_blocks, 256, 0, stream>>>(out, inv_out, W, hw, N);
    gather_kernel<<<gather_blocks, 256, 0, stream>>>(hw, inv_in, offsets, csr_src, b, out, N);
}

// Round 7
// 278.126 us; speedup vs baseline: 1.7584x; 1.0827x over previous
//
#include <hip/hip_runtime.h>
#include <hip/hip_fp16.h>

#define N_NODES 100000
#define N_EDGES 1600000
#define HDIM 64
#define NPB 512                                  // nodes per bucket (pow2)
#define NPB_SHIFT 9
#define NBUCK ((N_NODES + NPB - 1) / NPB)        // 196
#define NCHUNK 256                               // phase-A blocks (== blockDim of scan)
#define CHUNK (N_EDGES / NCHUNK)                 // 6250 edges/block

// ---------------- K1: per-chunk bucket histograms -> global (no global atomics) ----------------
__global__ void hist_kernel(const int* __restrict__ src, const int* __restrict__ dst,
                            int* __restrict__ hbD, int* __restrict__ hbS) {
    __shared__ int hD[NBUCK], hS[NBUCK];
    int t = threadIdx.x, blk = blockIdx.x;
    for (int i = t; i < NBUCK; i += 256) { hD[i] = 0; hS[i] = 0; }
    __syncthreads();
    int e0 = blk * CHUNK;
    for (int i = t; i < CHUNK; i += 256) {
        atomicAdd(&hD[dst[e0 + i] >> NPB_SHIFT], 1);
        atomicAdd(&hS[src[e0 + i] >> NPB_SHIFT], 1);
    }
    __syncthreads();
    for (int i = t; i < NBUCK; i += 256) {
        hbD[i * NCHUNK + blk] = hD[i];
        hbS[i * NCHUNK + blk] = hS[i];
    }
}

// ---------------- K2a: per-bucket scan across chunks -> chunk prefixes + bucket totals ----------------
__global__ void chunk_scan_kernel(const int* __restrict__ hbD, const int* __restrict__ hbS,
                                  int* __restrict__ pbD, int* __restrict__ pbS,
                                  int* __restrict__ totD, int* __restrict__ totS) {
    __shared__ int s[NCHUNK];
    int b = blockIdx.x, t = threadIdx.x;   // blockDim = NCHUNK
    int v = hbD[b * NCHUNK + t];
    s[t] = v;
    __syncthreads();
    for (int off = 1; off < NCHUNK; off <<= 1) {
        int x = (t >= off) ? s[t - off] : 0;
        __syncthreads(); s[t] += x; __syncthreads();
    }
    pbD[b * NCHUNK + t] = s[t] - v;
    if (t == NCHUNK - 1) totD[b] = s[t];
    __syncthreads();
    v = hbS[b * NCHUNK + t];
    s[t] = v;
    __syncthreads();
    for (int off = 1; off < NCHUNK; off <<= 1) {
        int x = (t >= off) ? s[t - off] : 0;
        __syncthreads(); s[t] += x; __syncthreads();
    }
    pbS[b * NCHUNK + t] = s[t] - v;
    if (t == NCHUNK - 1) totS[b] = s[t];
}

// ---------------- K2b: scan bucket totals -> bucket bases ----------------
__global__ void bucket_base_kernel(const int* __restrict__ totD, const int* __restrict__ totS,
                                   int* __restrict__ baseD, int* __restrict__ baseS) {
    __shared__ int s[256];
    int t = threadIdx.x;
    int v = (t < NBUCK) ? totD[t] : 0;
    s[t] = v;
    __syncthreads();
    for (int off = 1; off < 256; off <<= 1) {
        int x = (t >= off) ? s[t - off] : 0;
        __syncthreads(); s[t] += x; __syncthreads();
    }
    if (t < NBUCK) baseD[t] = s[t] - v;
    __syncthreads();
    v = (t < NBUCK) ? totS[t] : 0;
    s[t] = v;
    __syncthreads();
    for (int off = 1; off < 256; off <<= 1) {
        int x = (t >= off) ? s[t - off] : 0;
        __syncthreads(); s[t] += x; __syncthreads();
    }
    if (t < NBUCK) baseS[t] = s[t] - v;
}

// ---------------- K3: place edges into bucket-partitioned staging (LDS cursors only) ----------------
__global__ void place_kernel(const int* __restrict__ src, const int* __restrict__ dst,
                             const int* __restrict__ baseD, const int* __restrict__ pbD,
                             const int* __restrict__ baseS, const int* __restrict__ pbS,
                             unsigned int* __restrict__ bufD, unsigned short* __restrict__ bufS) {
    __shared__ int curD[NBUCK], curS[NBUCK];
    int t = threadIdx.x, blk = blockIdx.x;
    for (int i = t; i < NBUCK; i += 256) {
        curD[i] = baseD[i] + pbD[i * NCHUNK + blk];
        curS[i] = baseS[i] + pbS[i * NCHUNK + blk];
    }
    __syncthreads();
    int e0 = blk * CHUNK;
    for (int i = t; i < CHUNK; i += 256) {
        int s = src[e0 + i], d = dst[e0 + i];
        int pd = atomicAdd(&curD[d >> NPB_SHIFT], 1);
        bufD[pd] = (unsigned)s | ((unsigned)(d & (NPB - 1)) << 17);
        int ps = atomicAdd(&curS[s >> NPB_SHIFT], 1);
        bufS[ps] = (unsigned short)(s & (NPB - 1));
    }
}

// ---------------- K4: per dst-bucket: counts -> offsets/inv_in, place csr_src ----------------
__global__ void bucket_dst_kernel(const unsigned int* __restrict__ bufD,
                                  const int* __restrict__ baseD, const int* __restrict__ totD,
                                  int* __restrict__ csr_src, int* __restrict__ offsets,
                                  float* __restrict__ inv_in) {
    __shared__ int cnt[NPB], pre[NPB], cur[NPB];
    int b = blockIdx.x, t = threadIdx.x;   // blockDim = 512
    int ebase = baseD[b], ecnt = totD[b];
    cnt[t] = 0;
    __syncthreads();
    for (int i = t; i < ecnt; i += NPB)
        atomicAdd(&cnt[bufD[ebase + i] >> 17], 1);
    __syncthreads();
    int v = cnt[t];
    pre[t] = v;
    __syncthreads();
    for (int off = 1; off < NPB; off <<= 1) {
        int x = (t >= off) ? pre[t - off] : 0;
        __syncthreads(); pre[t] += x; __syncthreads();
    }
    int excl = pre[t] - v;
    cur[t] = excl;
    int node = b * NPB + t;
    if (node < N_NODES) {
        offsets[node] = ebase + excl;
        inv_in[node] = rsqrtf((float)max(v, 1));
    } else if (node == N_NODES) {
        offsets[N_NODES] = N_EDGES;
    }
    __syncthreads();
    for (int i = t; i < ecnt; i += NPB) {
        unsigned int en = bufD[ebase + i];
        int l = (int)(en >> 17);
        int pos = atomicAdd(&cur[l], 1);
        csr_src[ebase + pos] = (int)(en & 0x1FFFFu);
    }
}

// ---------------- K5: per src-bucket: counts -> inv_out ----------------
__global__ void bucket_src_kernel(const unsigned short* __restrict__ bufS,
                                  const int* __restrict__ baseS, const int* __restrict__ totS,
                                  float* __restrict__ inv_out) {
    __shared__ int cnt[NPB];
    int b = blockIdx.x, t = threadIdx.x;   // blockDim = 512
    int ebase = baseS[b], ecnt = totS[b];
    cnt[t] = 0;
    __syncthreads();
    for (int i = t; i < ecnt; i += NPB)
        atomicAdd(&cnt[(int)bufS[ebase + i]], 1);
    __syncthreads();
    int node = b * NPB + t;
    if (node < N_NODES) inv_out[node] = rsqrtf((float)max(cnt[t], 1));
}

__device__ inline uint2 f4_to_h4(float4 a) {
    __half2 lo = __floats2half2_rn(a.x, a.y);
    __half2 hi = __floats2half2_rn(a.z, a.w);
    uint2 r;
    r.x = *(unsigned*)&lo;
    r.y = *(unsigned*)&hi;
    return r;
}

// ---------------- dense: hw(fp16) = (h * inv_out[:,None]) @ W  (32 rows/block) ----------------
__global__ void dense_kernel(const float* __restrict__ h, const float* __restrict__ inv_out,
                             const float* __restrict__ W, uint2* __restrict__ hw, int n) {
    __shared__ float Wlds[HDIM * HDIM];     // 16 KB
    __shared__ float Alds[32][HDIM + 1];    // 8.1 KB
    int t = threadIdx.x;
    int r0 = blockIdx.x * 32;

    for (int i = t; i < HDIM * HDIM / 4; i += 256)
        ((float4*)Wlds)[i] = ((const float4*)W)[i];

    for (int i = t; i < 512; i += 256) {    // 32 rows x 16 float4
        int r = i >> 4;
        int c4 = i & 15;
        int row = r0 + r;
        float4 v = make_float4(0.f, 0.f, 0.f, 0.f);
        float s = 0.f;
        if (row < n) {
            v = ((const float4*)h)[(long long)row * 16 + c4];
            s = inv_out[row];
        }
        Alds[r][c4 * 4 + 0] = v.x * s;
        Alds[r][c4 * 4 + 1] = v.y * s;
        Alds[r][c4 * 4 + 2] = v.z * s;
        Alds[r][c4 * 4 + 3] = v.w * s;
    }
    __syncthreads();

    int tx = t & 15;        // col quad
    int ty = t >> 4;        // 16 row-pairs
    float4 acc0 = make_float4(0.f, 0.f, 0.f, 0.f);
    float4 acc1 = acc0;

#pragma unroll 8
    for (int k = 0; k < HDIM; ++k) {
        float4 w = ((const float4*)(Wlds + k * HDIM))[tx];
        float a0 = Alds[2 * ty + 0][k];
        float a1 = Alds[2 * ty + 1][k];
        acc0.x = fmaf(a0, w.x, acc0.x); acc0.y = fmaf(a0, w.y, acc0.y);
        acc0.z = fmaf(a0, w.z, acc0.z); acc0.w = fmaf(a0, w.w, acc0.w);
        acc1.x = fmaf(a1, w.x, acc1.x); acc1.y = fmaf(a1, w.y, acc1.y);
        acc1.z = fmaf(a1, w.z, acc1.z); acc1.w = fmaf(a1, w.w, acc1.w);
    }

    int rb = r0 + 2 * ty;
    if (rb + 0 < n) hw[(long long)(rb + 0) * 16 + tx] = f4_to_h4(acc0);
    if (rb + 1 < n) hw[(long long)(rb + 1) * 16 + tx] = f4_to_h4(acc1);
}

// ---------------- gather: out = relu(inv_in * sum_{in-edges} hw[src] + b) ----------------
// one wave per dst row; 4 groups of 16 lanes; fp16 row loads (8 B/lane), fp32 accumulate
__global__ void gather_kernel(const uint2* __restrict__ hw, const float* __restrict__ inv_in,
                              const int* __restrict__ offsets, const int* __restrict__ csr_src,
                              const float* __restrict__ bias, float* __restrict__ out, int n) {
    int t = threadIdx.x;
    int wave = t >> 6, lane = t & 63;
    int row = blockIdx.x * 4 + wave;
    if (row >= n) return;
    int group = lane >> 4, gl = lane & 15;

    int start = offsets[row];
    int end   = offsets[row + 1];

    float4 acc = make_float4(0.f, 0.f, 0.f, 0.f);
    for (int jb = start; jb < end; jb += 64) {
        int m = end - jb;
        if (m > 64) m = 64;
        int sidx = (lane < m) ? csr_src[jb + lane] : -1;
        int iters = (m + 3) >> 2;
#pragma unroll 4
        for (int it = 0; it < iters; ++it) {
            int jj = it * 4 + group;
            int s = __shfl(sidx, jj, 64);
            bool valid = (s >= 0);
            int s2 = valid ? s : 0;
            uint2 u = hw[(long long)s2 * 16 + gl];
            if (valid) {
                float2 f0 = __half22float2(*(__half2*)&u.x);
                float2 f1 = __half22float2(*(__half2*)&u.y);
                acc.x += f0.x; acc.y += f0.y; acc.z += f1.x; acc.w += f1.y;
            }
        }
    }
    acc.x += __shfl_down(acc.x, 32, 64);
    acc.y += __shfl_down(acc.y, 32, 64);
    acc.z += __shfl_down(acc.z, 32, 64);
    acc.w += __shfl_down(acc.w, 32, 64);
    acc.x += __shfl_down(acc.x, 16, 64);
    acc.y += __shfl_down(acc.y, 16, 64);
    acc.z += __shfl_down(acc.z, 16, 64);
    acc.w += __shfl_down(acc.w, 16, 64);

    if (group == 0) {
        float sc = inv_in[row];
        float4 b4 = ((const float4*)bias)[gl];
        float4 r;
        r.x = fmaxf(fmaf(acc.x, sc, b4.x), 0.f);
        r.y = fmaxf(fmaf(acc.y, sc, b4.y), 0.f);
        r.z = fmaxf(fmaf(acc.z, sc, b4.z), 0.f);
        r.w = fmaxf(fmaf(acc.w, sc, b4.w), 0.f);
        ((float4*)out)[(long long)row * 16 + gl] = r;
    }
}

extern "C" void kernel_launch(void* const* d_in, const int* in_sizes, int n_in,
                              void* d_out, int out_size, void* d_ws, size_t ws_size,
                              hipStream_t stream) {
    const float* features = (const float*)d_in[0];   // [N, 64]
    const float* W        = (const float*)d_in[1];   // [64, 64]
    const float* b        = (const float*)d_in[2];   // [64]
    const int*   src      = (const int*)d_in[3];     // [E]
    const int*   dst      = (const int*)d_in[4];     // [E]

    float* out = (float*)d_out;                      // [N, 64] — also inter-layer temp

    // workspace layout (4-byte words)
    float* ws = (float*)d_ws;
    uint2* hw = (uint2*)ws;                          // N*16 uint2 = 12.8 MB (fp16 rows)
    // --- overlay after hw (bufD/bufS dead before dense_kernel runs) ---
    unsigned int*   bufD = (unsigned int*)(ws + (size_t)N_NODES * 32);  // E words (6.4 MB)
    unsigned short* bufS = (unsigned short*)(bufD + N_EDGES);           // E u16   (3.2 MB)
    // --- persistent ---
    float* inv_out = (float*)(bufS + N_EDGES);       // N
    float* inv_in  = inv_out + N_NODES;              // N
    int*   offsets = (int*)(inv_in + N_NODES);       // N+1
    int*   csr_src = offsets + N_NODES + 1;          // E
    int*   hbD     = csr_src + N_EDGES;              // NBUCK*NCHUNK
    int*   hbS     = hbD + NBUCK * NCHUNK;           // NBUCK*NCHUNK
    int*   pbD     = hbS + NBUCK * NCHUNK;           // NBUCK*NCHUNK
    int*   pbS     = pbD + NBUCK * NCHUNK;           // NBUCK*NCHUNK
    int*   totD    = pbS + NBUCK * NCHUNK;           // NBUCK
    int*   totS    = totD + NBUCK;                   // NBUCK
    int*   baseD   = totS + NBUCK;                   // NBUCK
    int*   baseS   = baseD + NBUCK;                  // NBUCK

    const int N = N_NODES;

    // CSR + degrees via bucketed counting sort (zero global atomics)
    hist_kernel<<<NCHUNK, 256, 0, stream>>>(src, dst, hbD, hbS);
    chunk_scan_kernel<<<NBUCK, NCHUNK, 0, stream>>>(hbD, hbS, pbD, pbS, totD, totS);
    bucket_base_kernel<<<1, 256, 0, stream>>>(totD, totS, baseD, baseS);
    place_kernel<<<NCHUNK, 256, 0, stream>>>(src, dst, baseD, pbD, baseS, pbS, bufD, bufS);
    bucket_dst_kernel<<<NBUCK, NPB, 0, stream>>>(bufD, baseD, totD, csr_src, offsets, inv_in);
    bucket_src_kernel<<<NBUCK, NPB, 0, stream>>>(bufS, baseS, totS, inv_out);

    int dense_blocks  = (N + 31) / 32;
    int gather_blocks = (N + 3) / 4;

    // layer 1: features -> hw(fp16) -> out
    dense_kernel<<<dense_blocks, 256, 0, stream>>>(features, inv_out, W, hw, N);
    gather_kernel<<<gather_blocks, 256, 0, stream>>>(hw, inv_in, offsets, csr_src, b, out, N);

    // layer 2: out -> hw(fp16) -> out
    dense_kernel<<<dense_blocks, 256, 0, stream>>>(out, inv_out, W, hw, N);
    gather_kernel<<<gather_blocks, 256, 0, stream>>>(hw, inv_in, offsets, csr_src, b, out, N);
}

// Round 8
// 248.310 us; speedup vs baseline: 1.9695x; 1.1201x over previous
//
#include <hip/hip_runtime.h>
#include <hip/hip_fp16.h>

#define N_NODES 100000
#define N_EDGES 1600000
#define HDIM 64
#define NPB 512                                  // nodes per bucket (pow2)
#define NPB_SHIFT 9
#define NBUCK ((N_NODES + NPB - 1) / NPB)        // 196
#define NCHUNK 256                               // phase-A blocks (== blockDim of scan)
#define CHUNK (N_EDGES / NCHUNK)                 // 6250 edges/block

// ---------------- K1: per-chunk bucket histograms -> global (no global atomics) ----------------
__global__ void hist_kernel(const int* __restrict__ src, const int* __restrict__ dst,
                            int* __restrict__ hbD, int* __restrict__ hbS) {
    __shared__ int hD[NBUCK], hS[NBUCK];
    int t = threadIdx.x, blk = blockIdx.x;
    for (int i = t; i < NBUCK; i += 256) { hD[i] = 0; hS[i] = 0; }
    __syncthreads();
    int e0 = blk * CHUNK;
    for (int i = t; i < CHUNK; i += 256) {
        atomicAdd(&hD[dst[e0 + i] >> NPB_SHIFT], 1);
        atomicAdd(&hS[src[e0 + i] >> NPB_SHIFT], 1);
    }
    __syncthreads();
    for (int i = t; i < NBUCK; i += 256) {
        hbD[i * NCHUNK + blk] = hD[i];
        hbS[i * NCHUNK + blk] = hS[i];
    }
}

// ---------------- K2a: per-bucket scan across chunks -> chunk prefixes + bucket totals ----------------
__global__ void chunk_scan_kernel(const int* __restrict__ hbD, const int* __restrict__ hbS,
                                  int* __restrict__ pbD, int* __restrict__ pbS,
                                  int* __restrict__ totD, int* __restrict__ totS) {
    __shared__ int s[NCHUNK];
    int b = blockIdx.x, t = threadIdx.x;   // blockDim = NCHUNK
    int v = hbD[b * NCHUNK + t];
    s[t] = v;
    __syncthreads();
    for (int off = 1; off < NCHUNK; off <<= 1) {
        int x = (t >= off) ? s[t - off] : 0;
        __syncthreads(); s[t] += x; __syncthreads();
    }
    pbD[b * NCHUNK + t] = s[t] - v;
    if (t == NCHUNK - 1) totD[b] = s[t];
    __syncthreads();
    v = hbS[b * NCHUNK + t];
    s[t] = v;
    __syncthreads();
    for (int off = 1; off < NCHUNK; off <<= 1) {
        int x = (t >= off) ? s[t - off] : 0;
        __syncthreads(); s[t] += x; __syncthreads();
    }
    pbS[b * NCHUNK + t] = s[t] - v;
    if (t == NCHUNK - 1) totS[b] = s[t];
}

// ---------------- K2b: scan bucket totals -> bucket bases ----------------
__global__ void bucket_base_kernel(const int* __restrict__ totD, const int* __restrict__ totS,
                                   int* __restrict__ baseD, int* __restrict__ baseS) {
    __shared__ int s[256];
    int t = threadIdx.x;
    int v = (t < NBUCK) ? totD[t] : 0;
    s[t] = v;
    __syncthreads();
    for (int off = 1; off < 256; off <<= 1) {
        int x = (t >= off) ? s[t - off] : 0;
        __syncthreads(); s[t] += x; __syncthreads();
    }
    if (t < NBUCK) baseD[t] = s[t] - v;
    __syncthreads();
    v = (t < NBUCK) ? totS[t] : 0;
    s[t] = v;
    __syncthreads();
    for (int off = 1; off < 256; off <<= 1) {
        int x = (t >= off) ? s[t - off] : 0;
        __syncthreads(); s[t] += x; __syncthreads();
    }
    if (t < NBUCK) baseS[t] = s[t] - v;
}

// ---------------- K3: place edges into bucket-partitioned staging (LDS cursors only) ----------------
__global__ void place_kernel(const int* __restrict__ src, const int* __restrict__ dst,
                             const int* __restrict__ baseD, const int* __restrict__ pbD,
                             const int* __restrict__ baseS, const int* __restrict__ pbS,
                             unsigned int* __restrict__ bufD, unsigned short* __restrict__ bufS) {
    __shared__ int curD[NBUCK], curS[NBUCK];
    int t = threadIdx.x, blk = blockIdx.x;
    for (int i = t; i < NBUCK; i += 256) {
        curD[i] = baseD[i] + pbD[i * NCHUNK + blk];
        curS[i] = baseS[i] + pbS[i * NCHUNK + blk];
    }
    __syncthreads();
    int e0 = blk * CHUNK;
    for (int i = t; i < CHUNK; i += 256) {
        int s = src[e0 + i], d = dst[e0 + i];
        int pd = atomicAdd(&curD[d >> NPB_SHIFT], 1);
        bufD[pd] = (unsigned)s | ((unsigned)(d & (NPB - 1)) << 17);
        int ps = atomicAdd(&curS[s >> NPB_SHIFT], 1);
        bufS[ps] = (unsigned short)(s & (NPB - 1));
    }
}

// ---------------- K4: per dst-bucket: counts -> offsets/inv_in, place csr_src ----------------
__global__ void bucket_dst_kernel(const unsigned int* __restrict__ bufD,
                                  const int* __restrict__ baseD, const int* __restrict__ totD,
                                  int* __restrict__ csr_src, int* __restrict__ offsets,
                                  float* __restrict__ inv_in) {
    __shared__ int cnt[NPB], pre[NPB], cur[NPB];
    int b = blockIdx.x, t = threadIdx.x;   // blockDim = 512
    int ebase = baseD[b], ecnt = totD[b];
    cnt[t] = 0;
    __syncthreads();
    for (int i = t; i < ecnt; i += NPB)
        atomicAdd(&cnt[bufD[ebase + i] >> 17], 1);
    __syncthreads();
    int v = cnt[t];
    pre[t] = v;
    __syncthreads();
    for (int off = 1; off < NPB; off <<= 1) {
        int x = (t >= off) ? pre[t - off] : 0;
        __syncthreads(); pre[t] += x; __syncthreads();
    }
    int excl = pre[t] - v;
    cur[t] = excl;
    int node = b * NPB + t;
    if (node < N_NODES) {
        offsets[node] = ebase + excl;
        inv_in[node] = rsqrtf((float)max(v, 1));
    } else if (node == N_NODES) {
        offsets[N_NODES] = N_EDGES;
    }
    __syncthreads();
    for (int i = t; i < ecnt; i += NPB) {
        unsigned int en = bufD[ebase + i];
        int l = (int)(en >> 17);
        int pos = atomicAdd(&cur[l], 1);
        csr_src[ebase + pos] = (int)(en & 0x1FFFFu);
    }
}

// ---------------- K5: per src-bucket: counts -> inv_out ----------------
__global__ void bucket_src_kernel(const unsigned short* __restrict__ bufS,
                                  const int* __restrict__ baseS, const int* __restrict__ totS,
                                  float* __restrict__ inv_out) {
    __shared__ int cnt[NPB];
    int b = blockIdx.x, t = threadIdx.x;   // blockDim = 512
    int ebase = baseS[b], ecnt = totS[b];
    cnt[t] = 0;
    __syncthreads();
    for (int i = t; i < ecnt; i += NPB)
        atomicAdd(&cnt[(int)bufS[ebase + i]], 1);
    __syncthreads();
    int node = b * NPB + t;
    if (node < N_NODES) inv_out[node] = rsqrtf((float)max(cnt[t], 1));
}

__device__ inline uint2 f4_to_h4(float4 a) {
    __half2 lo = __floats2half2_rn(a.x, a.y);
    __half2 hi = __floats2half2_rn(a.z, a.w);
    uint2 r;
    r.x = *(unsigned*)&lo;
    r.y = *(unsigned*)&hi;
    return r;
}

// ---------------- dense: hw(fp16) = (h * inv_out[:,None]) @ W  (32 rows/block) ----------------
__global__ void dense_kernel(const float* __restrict__ h, const float* __restrict__ inv_out,
                             const float* __restrict__ W, uint2* __restrict__ hw, int n) {
    __shared__ float Wlds[HDIM * HDIM];     // 16 KB
    __shared__ float Alds[32][HDIM + 1];    // 8.1 KB
    int t = threadIdx.x;
    int r0 = blockIdx.x * 32;

    for (int i = t; i < HDIM * HDIM / 4; i += 256)
        ((float4*)Wlds)[i] = ((const float4*)W)[i];

    for (int i = t; i < 512; i += 256) {    // 32 rows x 16 float4
        int r = i >> 4;
        int c4 = i & 15;
        int row = r0 + r;
        float4 v = make_float4(0.f, 0.f, 0.f, 0.f);
        float s = 0.f;
        if (row < n) {
            v = ((const float4*)h)[(long long)row * 16 + c4];
            s = inv_out[row];
        }
        Alds[r][c4 * 4 + 0] = v.x * s;
        Alds[r][c4 * 4 + 1] = v.y * s;
        Alds[r][c4 * 4 + 2] = v.z * s;
        Alds[r][c4 * 4 + 3] = v.w * s;
    }
    __syncthreads();

    int tx = t & 15;        // col quad
    int ty = t >> 4;        // 16 row-pairs
    float4 acc0 = make_float4(0.f, 0.f, 0.f, 0.f);
    float4 acc1 = acc0;

#pragma unroll 8
    for (int k = 0; k < HDIM; ++k) {
        float4 w = ((const float4*)(Wlds + k * HDIM))[tx];
        float a0 = Alds[2 * ty + 0][k];
        float a1 = Alds[2 * ty + 1][k];
        acc0.x = fmaf(a0, w.x, acc0.x); acc0.y = fmaf(a0, w.y, acc0.y);
        acc0.z = fmaf(a0, w.z, acc0.z); acc0.w = fmaf(a0, w.w, acc0.w);
        acc1.x = fmaf(a1, w.x, acc1.x); acc1.y = fmaf(a1, w.y, acc1.y);
        acc1.z = fmaf(a1, w.z, acc1.z); acc1.w = fmaf(a1, w.w, acc1.w);
    }

    int rb = r0 + 2 * ty;
    if (rb + 0 < n) hw[(long long)(rb + 0) * 16 + tx] = f4_to_h4(acc0);
    if (rb + 1 < n) hw[(long long)(rb + 1) * 16 + tx] = f4_to_h4(acc1);
}

// ---------------- gather: out = relu(inv_in * sum_{in-edges} hw[src] + b) ----------------
// one 8-lane group per dst row (8 rows/wave, 32 rows/block); lane = 16B slice of the row.
// One dwordx4 load serves a full edge; no cross-group reduction needed.
__global__ void gather_kernel(const uint4* __restrict__ hw, const float* __restrict__ inv_in,
                              const int* __restrict__ offsets, const int* __restrict__ csr_src,
                              const float* __restrict__ bias, float* __restrict__ out, int n) {
    int t = threadIdx.x;
    int wave = t >> 6, lane = t & 63;
    int g = lane >> 3, gl = lane & 7;          // group 0..7, lane-in-group 0..7
    int row = blockIdx.x * 32 + wave * 8 + g;  // N = 3125 * 32 exactly
    if (row >= n) return;

    float acc0 = 0.f, acc1 = 0.f, acc2 = 0.f, acc3 = 0.f;
    float acc4 = 0.f, acc5 = 0.f, acc6 = 0.f, acc7 = 0.f;

    int start = offsets[row];
    int end   = offsets[row + 1];
    int gbase = g << 3;

    for (int jb = start; jb < end; jb += 8) {
        int mm = end - jb;
        if (mm > 8) mm = 8;
        int sidx = (gl < mm) ? csr_src[jb + gl] : 0;
        if (mm == 8) {
#pragma unroll
            for (int j = 0; j < 8; ++j) {
                int s = __shfl(sidx, gbase + j, 64);
                uint4 u = hw[(long long)s * 8 + gl];
                float2 f0 = __half22float2(*(__half2*)&u.x);
                float2 f1 = __half22float2(*(__half2*)&u.y);
                float2 f2 = __half22float2(*(__half2*)&u.z);
                float2 f3 = __half22float2(*(__half2*)&u.w);
                acc0 += f0.x; acc1 += f0.y; acc2 += f1.x; acc3 += f1.y;
                acc4 += f2.x; acc5 += f2.y; acc6 += f3.x; acc7 += f3.y;
            }
        } else {
            for (int j = 0; j < mm; ++j) {
                int s = __shfl(sidx, gbase + j, 64);
                uint4 u = hw[(long long)s * 8 + gl];
                float2 f0 = __half22float2(*(__half2*)&u.x);
                float2 f1 = __half22float2(*(__half2*)&u.y);
                float2 f2 = __half22float2(*(__half2*)&u.z);
                float2 f3 = __half22float2(*(__half2*)&u.w);
                acc0 += f0.x; acc1 += f0.y; acc2 += f1.x; acc3 += f1.y;
                acc4 += f2.x; acc5 += f2.y; acc6 += f3.x; acc7 += f3.y;
            }
        }
    }

    float sc = inv_in[row];
    float4 b0 = ((const float4*)bias)[gl * 2 + 0];
    float4 b1 = ((const float4*)bias)[gl * 2 + 1];
    float4 r0, r1;
    r0.x = fmaxf(fmaf(acc0, sc, b0.x), 0.f);
    r0.y = fmaxf(fmaf(acc1, sc, b0.y), 0.f);
    r0.z = fmaxf(fmaf(acc2, sc, b0.z), 0.f);
    r0.w = fmaxf(fmaf(acc3, sc, b0.w), 0.f);
    r1.x = fmaxf(fmaf(acc4, sc, b1.x), 0.f);
    r1.y = fmaxf(fmaf(acc5, sc, b1.y), 0.f);
    r1.z = fmaxf(fmaf(acc6, sc, b1.z), 0.f);
    r1.w = fmaxf(fmaf(acc7, sc, b1.w), 0.f);
    ((float4*)out)[(long long)row * 16 + gl * 2 + 0] = r0;
    ((float4*)out)[(long long)row * 16 + gl * 2 + 1] = r1;
}

extern "C" void kernel_launch(void* const* d_in, const int* in_sizes, int n_in,
                              void* d_out, int out_size, void* d_ws, size_t ws_size,
                              hipStream_t stream) {
    const float* features = (const float*)d_in[0];   // [N, 64]
    const float* W        = (const float*)d_in[1];   // [64, 64]
    const float* b        = (const float*)d_in[2];   // [64]
    const int*   src      = (const int*)d_in[3];     // [E]
    const int*   dst      = (const int*)d_in[4];     // [E]

    float* out = (float*)d_out;                      // [N, 64] — also inter-layer temp

    // workspace layout (4-byte words)
    float* ws = (float*)d_ws;
    uint2* hw = (uint2*)ws;                          // N*16 uint2 = 12.8 MB (fp16 rows)
    // --- overlay after hw (bufD/bufS dead before dense_kernel runs) ---
    unsigned int*   bufD = (unsigned int*)(ws + (size_t)N_NODES * 32);  // E words (6.4 MB)
    unsigned short* bufS = (unsigned short*)(bufD + N_EDGES);           // E u16   (3.2 MB)
    // --- persistent ---
    float* inv_out = (float*)(bufS + N_EDGES);       // N
    float* inv_in  = inv_out + N_NODES;              // N
    int*   offsets = (int*)(inv_in + N_NODES);       // N+1
    int*   csr_src = offsets + N_NODES + 1;          // E
    int*   hbD     = csr_src + N_EDGES;              // NBUCK*NCHUNK
    int*   hbS     = hbD + NBUCK * NCHUNK;           // NBUCK*NCHUNK
    int*   pbD     = hbS + NBUCK * NCHUNK;           // NBUCK*NCHUNK
    int*   pbS     = pbD + NBUCK * NCHUNK;           // NBUCK*NCHUNK
    int*   totD    = pbS + NBUCK * NCHUNK;           // NBUCK
    int*   totS    = totD + NBUCK;                   // NBUCK
    int*   baseD   = totS + NBUCK;                   // NBUCK
    int*   baseS   = baseD + NBUCK;                  // NBUCK

    const int N = N_NODES;

    // CSR + degrees via bucketed counting sort (zero global atomics)
    hist_kernel<<<NCHUNK, 256, 0, stream>>>(src, dst, hbD, hbS);
    chunk_scan_kernel<<<NBUCK, NCHUNK, 0, stream>>>(hbD, hbS, pbD, pbS, totD, totS);
    bucket_base_kernel<<<1, 256, 0, stream>>>(totD, totS, baseD, baseS);
    place_kernel<<<NCHUNK, 256, 0, stream>>>(src, dst, baseD, pbD, baseS, pbS, bufD, bufS);
    bucket_dst_kernel<<<NBUCK, NPB, 0, stream>>>(bufD, baseD, totD, csr_src, offsets, inv_in);
    bucket_src_kernel<<<NBUCK, NPB, 0, stream>>>(bufS, baseS, totS, inv_out);

    int dense_blocks  = (N + 31) / 32;
    int gather_blocks = (N + 31) / 32;   // 32 rows per block

    // layer 1: features -> hw(fp16) -> out
    dense_kernel<<<dense_blocks, 256, 0, stream>>>(features, inv_out, W, hw, N);
    gather_kernel<<<gather_blocks, 256, 0, stream>>>((const uint4*)hw, inv_in, offsets, csr_src, b, out, N);

    // layer 2: out -> hw(fp16) -> out
    dense_kernel<<<dense_blocks, 256, 0, stream>>>(out, inv_out, W, hw, N);
    gather_kernel<<<gather_blocks, 256, 0, stream>>>((const uint4*)hw, inv_in, offsets, csr_src, b, out, N);
}